// Round 12
// baseline (81.578 us; speedup 1.0000x reference)
//
#include <hip/hip_runtime.h>

#define OUTS 7
#define SR 2
#define GRIDW 14   // OUTS*SR
#define NS 196     // 14*14 sample points per roi
#define NCH 256
#define NROI 1024
#define NBIN 49

// bf16 NHWC workspace layout (ushort elements):
#define L0_OFF 0
#define L1_OFF 20480000
#define L2_OFF 25600000
#define L3_OFF 26880000
#define WS_ELEMS 27200000          // ushort elements (54.4 MB)

#define TSTRIDE 1032               // LDS row stride (ushort) for 1024-px tile

static __device__ __forceinline__ unsigned short f2bf(float f) {
    unsigned u = __builtin_bit_cast(unsigned, f);
    u += 0x7fffu + ((u >> 16) & 1u);   // round-to-nearest-even
    return (unsigned short)(u >> 16);
}

static __device__ __forceinline__ float bfhi(unsigned u) {
    return __builtin_bit_cast(float, u & 0xffff0000u);
}
static __device__ __forceinline__ float bflo(unsigned u) {
    return __builtin_bit_cast(float, u << 16);
}

// Transpose NCHW f32 -> NHWC bf16, PAGE-EXCLUSIVE read variant (TLB test).
// Block = 16 channels x 1024 pixels: each block reads sixteen complete 4-KB
// channel-rows sequentially and exclusively (1 PTE fetch per input page,
// ~1 page live per wave). FIXED vs r11: load loop is 16 iters (full 1024 px),
// not 4 (which left 3/4 of LDS uninitialized -> NaN).
__global__ __launch_bounds__(256) void nchw_to_nhwc_bf16(
    const float* __restrict__ f0, const float* __restrict__ f1,
    const float* __restrict__ f2, const float* __restrict__ f3,
    unsigned short* __restrict__ ws) {
    __shared__ unsigned short tile[16 * TSTRIDE];   // 33,024 B
    int bid = blockIdx.x;
    const float* in; unsigned short* outp; int P, ptiles, local;
    // blocks per level = ptiles * 16 ctiles * 2 batches
    if (bid < 1280)      { in = f0; outp = ws + L0_OFF; P = 40000; ptiles = 40; local = bid; }
    else if (bid < 1600) { in = f1; outp = ws + L1_OFF; P = 10000; ptiles = 10; local = bid - 1280; }
    else if (bid < 1696) { in = f2; outp = ws + L2_OFF; P = 2500;  ptiles = 3;  local = bid - 1600; }
    else                 { in = f3; outp = ws + L3_OFF; P = 625;   ptiles = 1;  local = bid - 1696; }
    int ct = local & 15;            // channel tile
    int rest = local >> 4;
    int pt = rest % ptiles;
    int b  = rest / ptiles;
    int p0 = pt * 1024;
    int t = threadIdx.x;

    const float* inb = in + (size_t)(b * NCH + ct * 16) * P + p0;
    unsigned short* outb = outp + (size_t)b * P * NCH + ct * 16;

    // ---- load phase: thread t -> channel c = t>>4, float4-chunk k4 = t&15;
    //      16 iterations cover all 1024 px of the channel row ----
    {
        int c = t >> 4;
        int k4 = t & 15;
        const float* src = inb + (size_t)c * P;
        unsigned short* trow = &tile[c * TSTRIDE];
        bool vec_ok = ((P & 3) == 0);
#pragma unroll
        for (int it = 0; it < 16; ++it) {
            int px = (k4 + it * 16) * 4;
            unsigned short pk[4];
            if (vec_ok && (p0 + px + 3 < P)) {
                float4 v = *(const float4*)(src + px);
                pk[0] = f2bf(v.x); pk[1] = f2bf(v.y);
                pk[2] = f2bf(v.z); pk[3] = f2bf(v.w);
            } else {
#pragma unroll
                for (int k = 0; k < 4; ++k)
                    pk[k] = (p0 + px + k < P) ? f2bf(src[px + k]) : (unsigned short)0;
            }
            uint2 u;
            u.x = (unsigned)pk[0] | ((unsigned)pk[1] << 16);
            u.y = (unsigned)pk[2] | ((unsigned)pk[3] << 16);
            *(uint2*)&trow[px] = u;
        }
    }
    __syncthreads();

    // ---- store phase: thread t -> pixels t, t+256, t+512, t+768 ----
#pragma unroll
    for (int it = 0; it < 4; ++it) {
        int p = t + it * 256;
        int gp = p0 + p;
        if (gp < P) {
            unsigned pk[8];
#pragma unroll
            for (int m = 0; m < 8; ++m) {
                unsigned lo = tile[(2 * m) * TSTRIDE + p];
                unsigned hi = tile[(2 * m + 1) * TSTRIDE + p];
                pk[m] = lo | (hi << 16);
            }
            unsigned short* dst = outb + (size_t)gp * NCH;
            *(uint4*)dst       = make_uint4(pk[0], pk[1], pk[2], pk[3]);
            *(uint4*)(dst + 8) = make_uint4(pk[4], pk[5], pk[6], pk[7]);
        }
    }
}

// Gather: block = (roi, channel-quarter q) — unchanged (at HBM roofline).
__global__ __launch_bounds__(256) void roi_gather_nhwc(
    const unsigned short* __restrict__ nhwc,
    const float* __restrict__ rois,
    float* __restrict__ out) {
    __shared__ int   s_off[4][NS];
    __shared__ float s_w[4][NS];
    __shared__ float lds_out[64 * 53];    // [c_local][bin], stride 53

    int n = blockIdx.x >> 2;
    int q = blockIdx.x & 3;
    int tid = threadIdx.x;
    int b = n >> 9;

    float x1 = rois[n * 4 + 0];
    float y1 = rois[n * 4 + 1];
    float x2 = rois[n * 4 + 2];
    float y2 = rois[n * 4 + 3];
    float area = (y2 - y1) * (x2 - x1);
    float kf = floorf(4.0f + log2f(sqrtf(area) / 224.0f));
    kf = fminf(fmaxf(kf, 2.0f), 5.0f);
    int lvl = (int)kf - 2;
    float scale = ldexpf(0.25f, -lvl);
    int H, W; size_t base;
    switch (lvl) {
        case 0:  H = 200; W = 200; base = L0_OFF; break;
        case 1:  H = 100; W = 100; base = L1_OFF; break;
        case 2:  H = 50;  W = 50;  base = L2_OFF; break;
        default: H = 25;  W = 25;  base = L3_OFF; break;
    }
    float x1s = x1 * scale, y1s = y1 * scale;
    float rw = fmaxf(x2 * scale - x1s, 1.0f);
    float rh = fmaxf(y2 * scale - y1s, 1.0f);
    float sx = rw * (1.0f / GRIDW);
    float sy = rh * (1.0f / GRIDW);

    if (tid < NS) {
        int gy = tid / GRIDW, gx = tid % GRIDW;
        float y = y1s + ((float)gy + 0.5f) * sy;
        float x = x1s + ((float)gx + 0.5f) * sx;
        bool valid = (y >= -1.0f) && (y <= (float)H) && (x >= -1.0f) && (x <= (float)W);
        float yc = fminf(fmaxf(y, 0.0f), (float)(H - 1));
        float xc = fminf(fmaxf(x, 0.0f), (float)(W - 1));
        int y0 = (int)floorf(yc), x0 = (int)floorf(xc);
        int y1i = min(y0 + 1, H - 1), x1i = min(x0 + 1, W - 1);
        float ly = yc - (float)y0, lx = xc - (float)x0;
        float hy = 1.0f - ly, hx = 1.0f - lx;
        float vm = valid ? 1.0f : 0.0f;
        s_off[0][tid] = (y0 * W + x0) * NCH;
        s_off[1][tid] = (y0 * W + x1i) * NCH;
        s_off[2][tid] = (y1i * W + x0) * NCH;
        s_off[3][tid] = (y1i * W + x1i) * NCH;
        s_w[0][tid] = hy * hx * vm;
        s_w[1][tid] = hy * lx * vm;
        s_w[2][tid] = ly * hx * vm;
        s_w[3][tid] = ly * lx * vm;
    }
    __syncthreads();

    int lane = tid & 63;
    int wave = tid >> 6;
    int t = lane >> 4;      // tap index 0..3
    int j = lane & 15;      // channel chunk (4 ch)
    const unsigned short* fcq =
        nhwc + base + (size_t)b * (size_t)H * W * NCH + q * 64 + j * 4;

    for (int bin = wave; bin < NBIN; bin += 4) {
        int ph = bin / OUTS, pw = bin - ph * OUTS;
        int sbase = (ph * SR) * GRIDW + pw * SR;
        float4 acc = make_float4(0.f, 0.f, 0.f, 0.f);
#pragma unroll
        for (int k = 0; k < 4; ++k) {
            int s = sbase + (k >> 1) * GRIDW + (k & 1);
            float wgt = s_w[t][s];
            uint2 v = *(const uint2*)(fcq + s_off[t][s]);
            acc.x += wgt * bflo(v.x);
            acc.y += wgt * bfhi(v.x);
            acc.z += wgt * bflo(v.y);
            acc.w += wgt * bfhi(v.y);
        }
        acc.x += __shfl_xor(acc.x, 16, 64);
        acc.y += __shfl_xor(acc.y, 16, 64);
        acc.z += __shfl_xor(acc.z, 16, 64);
        acc.w += __shfl_xor(acc.w, 16, 64);
        acc.x += __shfl_xor(acc.x, 32, 64);
        acc.y += __shfl_xor(acc.y, 32, 64);
        acc.z += __shfl_xor(acc.z, 32, 64);
        acc.w += __shfl_xor(acc.w, 32, 64);
        if (t == 0) {
            lds_out[(4 * j + 0) * 53 + bin] = acc.x * 0.25f;
            lds_out[(4 * j + 1) * 53 + bin] = acc.y * 0.25f;
            lds_out[(4 * j + 2) * 53 + bin] = acc.z * 0.25f;
            lds_out[(4 * j + 3) * 53 + bin] = acc.w * 0.25f;
        }
    }
    __syncthreads();

    float* og = out + (size_t)n * (NCH * NBIN) + (size_t)q * 64 * NBIN;
    for (int i = tid; i < 64 * NBIN; i += 256) {
        int c = i / NBIN;
        int bin = i - c * NBIN;
        og[i] = lds_out[c * 53 + bin];
    }
}

// ---------------- fallback path (round-1, known-correct) ----------------

struct RoiMeta {
    float x1, y1, sx, sy;
    int level, b, pad0, pad1;
};

__global__ void prep_rois_kernel(const float* __restrict__ rois,
                                 RoiMeta* __restrict__ meta, int total) {
    int n = blockIdx.x * blockDim.x + threadIdx.x;
    if (n >= total) return;
    float x1 = rois[n * 4 + 0];
    float y1 = rois[n * 4 + 1];
    float x2 = rois[n * 4 + 2];
    float y2 = rois[n * 4 + 3];
    float area = (y2 - y1) * (x2 - x1);
    float k = floorf(4.0f + log2f(sqrtf(area) / 224.0f));
    k = fminf(fmaxf(k, 2.0f), 5.0f);
    int lvl = (int)k - 2;
    float scale = ldexpf(0.25f, -lvl);
    float x1s = x1 * scale;
    float y1s = y1 * scale;
    float rw = fmaxf(x2 * scale - x1s, 1.0f);
    float rh = fmaxf(y2 * scale - y1s, 1.0f);
    RoiMeta m;
    m.x1 = x1s; m.y1 = y1s;
    m.sx = rw / (float)(OUTS * SR);
    m.sy = rh / (float)(OUTS * SR);
    m.level = lvl;
    m.b = n / 512;
    m.pad0 = 0; m.pad1 = 0;
    meta[n] = m;
}

__global__ __launch_bounds__(256) void roi_align_kernel(
    const float* __restrict__ f0, const float* __restrict__ f1,
    const float* __restrict__ f2, const float* __restrict__ f3,
    const RoiMeta* __restrict__ meta, float* __restrict__ out, int total) {
    int idx = blockIdx.x * 256 + threadIdx.x;
    if (idx >= total) return;
    int pw = idx % OUTS;
    int ph = (idx / OUTS) % OUTS;
    int c  = (idx / (OUTS * OUTS)) & (NCH - 1);
    int n  = idx / (OUTS * OUTS * NCH);

    RoiMeta m = meta[n];
    const float* f; int H, W;
    switch (m.level) {
        case 0:  f = f0; H = 200; W = 200; break;
        case 1:  f = f1; H = 100; W = 100; break;
        case 2:  f = f2; H = 50;  W = 50;  break;
        default: f = f3; H = 25;  W = 25;  break;
    }
    const float* fc = f + (size_t)(m.b * NCH + c) * H * W;

    float acc = 0.0f;
#pragma unroll
    for (int iy = 0; iy < SR; ++iy) {
        float y = m.y1 + ((float)(ph * SR + iy) + 0.5f) * m.sy;
        if (y < -1.0f || y > (float)H) continue;
        float yc = fminf(fmaxf(y, 0.0f), (float)(H - 1));
        int y0 = (int)floorf(yc);
        int y1i = min(y0 + 1, H - 1);
        float ly = yc - (float)y0;
        float hy = 1.0f - ly;
        const float* r0 = fc + (size_t)y0 * W;
        const float* r1 = fc + (size_t)y1i * W;
#pragma unroll
        for (int ix = 0; ix < SR; ++ix) {
            float x = m.x1 + ((float)(pw * SR + ix) + 0.5f) * m.sx;
            if (x < -1.0f || x > (float)W) continue;
            float xc = fminf(fmaxf(x, 0.0f), (float)(W - 1));
            int x0 = (int)floorf(xc);
            int x1i = min(x0 + 1, W - 1);
            float lx = xc - (float)x0;
            float hx = 1.0f - lx;
            acc += hy * (hx * r0[x0] + lx * r0[x1i]) +
                   ly * (hx * r1[x0] + lx * r1[x1i]);
        }
    }
    out[idx] = acc * 0.25f;
}

// ---------------- launch ----------------

extern "C" void kernel_launch(void* const* d_in, const int* in_sizes, int n_in,
                              void* d_out, int out_size, void* d_ws, size_t ws_size,
                              hipStream_t stream) {
    const float* f0 = (const float*)d_in[0];
    const float* f1 = (const float*)d_in[1];
    const float* f2 = (const float*)d_in[2];
    const float* f3 = (const float*)d_in[3];
    const float* rois = (const float*)d_in[4];
    float* out = (float*)d_out;

    if (ws_size >= (size_t)WS_ELEMS * sizeof(unsigned short)) {
        unsigned short* nhwc = (unsigned short*)d_ws;
        nchw_to_nhwc_bf16<<<1728, 256, 0, stream>>>(f0, f1, f2, f3, nhwc);
        roi_gather_nhwc<<<NROI * 4, 256, 0, stream>>>(nhwc, rois, out);
    } else {
        RoiMeta* meta = (RoiMeta*)d_ws;
        prep_rois_kernel<<<(NROI + 255) / 256, 256, 0, stream>>>(rois, meta, NROI);
        const int total = NROI * NCH * OUTS * OUTS;
        roi_align_kernel<<<(total + 255) / 256, 256, 0, stream>>>(
            f0, f1, f2, f3, meta, out, total);
    }
}

// Round 13
// 68.067 us; speedup vs baseline: 1.1985x; 1.1985x over previous
//
#include <hip/hip_runtime.h>

#define OUTS 7
#define SR 2
#define GRIDW 14   // OUTS*SR
#define NS 196     // 14*14 sample points per roi
#define NCH 256
#define NROI 1024
#define NBIN 49

// bf16 NHWC workspace layout (ushort elements):
#define L0_OFF 0
#define L1_OFF 20480000
#define L2_OFF 25600000
#define L3_OFF 26880000
#define WS_ELEMS 27200000          // ushort elements (54.4 MB)

static __device__ __forceinline__ unsigned short f2bf(float f) {
    unsigned u = __builtin_bit_cast(unsigned, f);
    u += 0x7fffu + ((u >> 16) & 1u);   // round-to-nearest-even
    return (unsigned short)(u >> 16);
}

static __device__ __forceinline__ float bfhi(unsigned u) {
    return __builtin_bit_cast(float, u & 0xffff0000u);
}
static __device__ __forceinline__ float bflo(unsigned u) {
    return __builtin_bit_cast(float, u << 16);
}

// Transpose NCHW f32 -> NHWC bf16. Tile 64ch x 64px, f32 LDS stride 66,
// XOR px-swizzle so the ch-major read phase is conflict-free.
// (Best-measured variant: input read is allocation-bound at ~2.3 TB/s;
// 7 structural variants falsified pattern/occupancy/MLP/TLB theories.)
__global__ __launch_bounds__(256) void nchw_to_nhwc_bf16(
    const float* __restrict__ f0, const float* __restrict__ f1,
    const float* __restrict__ f2, const float* __restrict__ f3,
    unsigned short* __restrict__ ws) {
    __shared__ float tile[64 * 66];
    int bid = blockIdx.x;
    const float* in; unsigned short* outp; int P, ptiles, local;
    if (bid < 5000)      { in = f0; outp = ws + L0_OFF; P = 40000; ptiles = 625; local = bid; }
    else if (bid < 6256) { in = f1; outp = ws + L1_OFF; P = 10000; ptiles = 157; local = bid - 5000; }
    else if (bid < 6576) { in = f2; outp = ws + L2_OFF; P = 2500;  ptiles = 40;  local = bid - 6256; }
    else                 { in = f3; outp = ws + L3_OFF; P = 625;   ptiles = 10;  local = bid - 6576; }
    int pt = local % ptiles;
    int rest = local / ptiles;
    int c0 = (rest & 3) * 64;
    int b  = rest >> 2;
    int p0 = pt * 64;
    int t = threadIdx.x;
    int l = t & 63, w = t >> 6;

    const float* inb = in + (size_t)(b * NCH + c0) * P;
    unsigned short* outb = outp + (size_t)b * P * NCH;

    // ---- load phase: 4 x float4 per thread ----
    {
        int px = (l & 15) * 4;
        int p = p0 + px;
        if ((P & 3) == 0) {
#pragma unroll
            for (int i = 0; i < 4; ++i) {
                int c = w * 16 + i * 4 + (l >> 4);
                if (p < P) {
                    float4 v = *(const float4*)(inb + (size_t)c * P + p);
                    int pxs = px ^ (((c >> 2) & 7) << 2);
                    *(float2*)&tile[c * 66 + pxs]     = make_float2(v.x, v.y);
                    *(float2*)&tile[c * 66 + pxs + 2] = make_float2(v.z, v.w);
                }
            }
        } else {
#pragma unroll
            for (int i = 0; i < 4; ++i) {
                int c = w * 16 + i * 4 + (l >> 4);
                int pxs = px ^ (((c >> 2) & 7) << 2);
                const float* src = inb + (size_t)c * P;
#pragma unroll
                for (int k = 0; k < 4; ++k) {
                    tile[c * 66 + pxs + k] = (p + k < P) ? src[p + k] : 0.0f;
                }
            }
        }
    }
    __syncthreads();

    // ---- store phase: read 4ch x f32, pack to 4x bf16 = uint2, store ----
    {
        int j = t & 15;     // channel quad
        int pb = t >> 4;    // 0..15
        int S = (j & 7) << 2;
#pragma unroll
        for (int it = 0; it < 4; ++it) {
            int pp = pb + it * 16;
            int p = p0 + pp;
            if (p < P) {
                int pxs = pp ^ S;
                float a0 = tile[(4 * j + 0) * 66 + pxs];
                float a1 = tile[(4 * j + 1) * 66 + pxs];
                float a2 = tile[(4 * j + 2) * 66 + pxs];
                float a3 = tile[(4 * j + 3) * 66 + pxs];
                unsigned u0 = (unsigned)f2bf(a0) | ((unsigned)f2bf(a1) << 16);
                unsigned u1 = (unsigned)f2bf(a2) | ((unsigned)f2bf(a3) << 16);
                *(uint2*)(outb + (size_t)p * NCH + c0 + 4 * j) = make_uint2(u0, u1);
            }
        }
    }
}

// Gather: block = (roi, channel-quarter q). Block q computes ALL 49 bins for
// channels [64q, 64q+64) -> private contiguous 12544-B output region and
// disjoint 128-B feature sub-slices. lane = (tap t, ch-chunk j): one
// wave-load = 4 taps x 64ch of one sample; tap reduction via shfl_xor(16/32).
__global__ __launch_bounds__(256) void roi_gather_nhwc(
    const unsigned short* __restrict__ nhwc,
    const float* __restrict__ rois,
    float* __restrict__ out) {
    __shared__ int   s_off[4][NS];
    __shared__ float s_w[4][NS];
    __shared__ float lds_out[64 * 53];    // [c_local][bin], stride 53

    int n = blockIdx.x >> 2;
    int q = blockIdx.x & 3;
    int tid = threadIdx.x;
    int b = n >> 9;

    float x1 = rois[n * 4 + 0];
    float y1 = rois[n * 4 + 1];
    float x2 = rois[n * 4 + 2];
    float y2 = rois[n * 4 + 3];
    float area = (y2 - y1) * (x2 - x1);
    float kf = floorf(4.0f + log2f(sqrtf(area) / 224.0f));
    kf = fminf(fmaxf(kf, 2.0f), 5.0f);
    int lvl = (int)kf - 2;
    float scale = ldexpf(0.25f, -lvl);
    int H, W; size_t base;
    switch (lvl) {
        case 0:  H = 200; W = 200; base = L0_OFF; break;
        case 1:  H = 100; W = 100; base = L1_OFF; break;
        case 2:  H = 50;  W = 50;  base = L2_OFF; break;
        default: H = 25;  W = 25;  base = L3_OFF; break;
    }
    float x1s = x1 * scale, y1s = y1 * scale;
    float rw = fmaxf(x2 * scale - x1s, 1.0f);
    float rh = fmaxf(y2 * scale - y1s, 1.0f);
    float sx = rw * (1.0f / GRIDW);
    float sy = rh * (1.0f / GRIDW);

    if (tid < NS) {
        int gy = tid / GRIDW, gx = tid % GRIDW;
        float y = y1s + ((float)gy + 0.5f) * sy;
        float x = x1s + ((float)gx + 0.5f) * sx;
        bool valid = (y >= -1.0f) && (y <= (float)H) && (x >= -1.0f) && (x <= (float)W);
        float yc = fminf(fmaxf(y, 0.0f), (float)(H - 1));
        float xc = fminf(fmaxf(x, 0.0f), (float)(W - 1));
        int y0 = (int)floorf(yc), x0 = (int)floorf(xc);
        int y1i = min(y0 + 1, H - 1), x1i = min(x0 + 1, W - 1);
        float ly = yc - (float)y0, lx = xc - (float)x0;
        float hy = 1.0f - ly, hx = 1.0f - lx;
        float vm = valid ? 1.0f : 0.0f;
        s_off[0][tid] = (y0 * W + x0) * NCH;
        s_off[1][tid] = (y0 * W + x1i) * NCH;
        s_off[2][tid] = (y1i * W + x0) * NCH;
        s_off[3][tid] = (y1i * W + x1i) * NCH;
        s_w[0][tid] = hy * hx * vm;
        s_w[1][tid] = hy * lx * vm;
        s_w[2][tid] = ly * hx * vm;
        s_w[3][tid] = ly * lx * vm;
    }
    __syncthreads();

    int lane = tid & 63;
    int wave = tid >> 6;
    int t = lane >> 4;      // tap index 0..3
    int j = lane & 15;      // channel chunk (4 ch)
    const unsigned short* fcq =
        nhwc + base + (size_t)b * (size_t)H * W * NCH + q * 64 + j * 4;

    for (int bin = wave; bin < NBIN; bin += 4) {
        int ph = bin / OUTS, pw = bin - ph * OUTS;
        int sbase = (ph * SR) * GRIDW + pw * SR;
        float4 acc = make_float4(0.f, 0.f, 0.f, 0.f);
#pragma unroll
        for (int k = 0; k < 4; ++k) {
            int s = sbase + (k >> 1) * GRIDW + (k & 1);
            float wgt = s_w[t][s];
            uint2 v = *(const uint2*)(fcq + s_off[t][s]);
            acc.x += wgt * bflo(v.x);
            acc.y += wgt * bfhi(v.x);
            acc.z += wgt * bflo(v.y);
            acc.w += wgt * bfhi(v.y);
        }
        acc.x += __shfl_xor(acc.x, 16, 64);
        acc.y += __shfl_xor(acc.y, 16, 64);
        acc.z += __shfl_xor(acc.z, 16, 64);
        acc.w += __shfl_xor(acc.w, 16, 64);
        acc.x += __shfl_xor(acc.x, 32, 64);
        acc.y += __shfl_xor(acc.y, 32, 64);
        acc.z += __shfl_xor(acc.z, 32, 64);
        acc.w += __shfl_xor(acc.w, 32, 64);
        if (t == 0) {
            lds_out[(4 * j + 0) * 53 + bin] = acc.x * 0.25f;
            lds_out[(4 * j + 1) * 53 + bin] = acc.y * 0.25f;
            lds_out[(4 * j + 2) * 53 + bin] = acc.z * 0.25f;
            lds_out[(4 * j + 3) * 53 + bin] = acc.w * 0.25f;
        }
    }
    __syncthreads();

    float* og = out + (size_t)n * (NCH * NBIN) + (size_t)q * 64 * NBIN;
    for (int i = tid; i < 64 * NBIN; i += 256) {
        int c = i / NBIN;
        int bin = i - c * NBIN;
        og[i] = lds_out[c * 53 + bin];
    }
}

// ---------------- fallback path (round-1, known-correct) ----------------

struct RoiMeta {
    float x1, y1, sx, sy;
    int level, b, pad0, pad1;
};

__global__ void prep_rois_kernel(const float* __restrict__ rois,
                                 RoiMeta* __restrict__ meta, int total) {
    int n = blockIdx.x * blockDim.x + threadIdx.x;
    if (n >= total) return;
    float x1 = rois[n * 4 + 0];
    float y1 = rois[n * 4 + 1];
    float x2 = rois[n * 4 + 2];
    float y2 = rois[n * 4 + 3];
    float area = (y2 - y1) * (x2 - x1);
    float k = floorf(4.0f + log2f(sqrtf(area) / 224.0f));
    k = fminf(fmaxf(k, 2.0f), 5.0f);
    int lvl = (int)k - 2;
    float scale = ldexpf(0.25f, -lvl);
    float x1s = x1 * scale;
    float y1s = y1 * scale;
    float rw = fmaxf(x2 * scale - x1s, 1.0f);
    float rh = fmaxf(y2 * scale - y1s, 1.0f);
    RoiMeta m;
    m.x1 = x1s; m.y1 = y1s;
    m.sx = rw / (float)(OUTS * SR);
    m.sy = rh / (float)(OUTS * SR);
    m.level = lvl;
    m.b = n / 512;
    m.pad0 = 0; m.pad1 = 0;
    meta[n] = m;
}

__global__ __launch_bounds__(256) void roi_align_kernel(
    const float* __restrict__ f0, const float* __restrict__ f1,
    const float* __restrict__ f2, const float* __restrict__ f3,
    const RoiMeta* __restrict__ meta, float* __restrict__ out, int total) {
    int idx = blockIdx.x * 256 + threadIdx.x;
    if (idx >= total) return;
    int pw = idx % OUTS;
    int ph = (idx / OUTS) % OUTS;
    int c  = (idx / (OUTS * OUTS)) & (NCH - 1);
    int n  = idx / (OUTS * OUTS * NCH);

    RoiMeta m = meta[n];
    const float* f; int H, W;
    switch (m.level) {
        case 0:  f = f0; H = 200; W = 200; break;
        case 1:  f = f1; H = 100; W = 100; break;
        case 2:  f = f2; H = 50;  W = 50;  break;
        default: f = f3; H = 25;  W = 25;  break;
    }
    const float* fc = f + (size_t)(m.b * NCH + c) * H * W;

    float acc = 0.0f;
#pragma unroll
    for (int iy = 0; iy < SR; ++iy) {
        float y = m.y1 + ((float)(ph * SR + iy) + 0.5f) * m.sy;
        if (y < -1.0f || y > (float)H) continue;
        float yc = fminf(fmaxf(y, 0.0f), (float)(H - 1));
        int y0 = (int)floorf(yc);
        int y1i = min(y0 + 1, H - 1);
        float ly = yc - (float)y0;
        float hy = 1.0f - ly;
        const float* r0 = fc + (size_t)y0 * W;
        const float* r1 = fc + (size_t)y1i * W;
#pragma unroll
        for (int ix = 0; ix < SR; ++ix) {
            float x = m.x1 + ((float)(pw * SR + ix) + 0.5f) * m.sx;
            if (x < -1.0f || x > (float)W) continue;
            float xc = fminf(fmaxf(x, 0.0f), (float)(W - 1));
            int x0 = (int)floorf(xc);
            int x1i = min(x0 + 1, W - 1);
            float lx = xc - (float)x0;
            float hx = 1.0f - lx;
            acc += hy * (hx * r0[x0] + lx * r0[x1i]) +
                   ly * (hx * r1[x0] + lx * r1[x1i]);
        }
    }
    out[idx] = acc * 0.25f;
}

// ---------------- launch ----------------

extern "C" void kernel_launch(void* const* d_in, const int* in_sizes, int n_in,
                              void* d_out, int out_size, void* d_ws, size_t ws_size,
                              hipStream_t stream) {
    const float* f0 = (const float*)d_in[0];
    const float* f1 = (const float*)d_in[1];
    const float* f2 = (const float*)d_in[2];
    const float* f3 = (const float*)d_in[3];
    const float* rois = (const float*)d_in[4];
    float* out = (float*)d_out;

    if (ws_size >= (size_t)WS_ELEMS * sizeof(unsigned short)) {
        unsigned short* nhwc = (unsigned short*)d_ws;
        nchw_to_nhwc_bf16<<<6656, 256, 0, stream>>>(f0, f1, f2, f3, nhwc);
        roi_gather_nhwc<<<NROI * 4, 256, 0, stream>>>(nhwc, rois, out);
    } else {
        RoiMeta* meta = (RoiMeta*)d_ws;
        prep_rois_kernel<<<(NROI + 255) / 256, 256, 0, stream>>>(rois, meta, NROI);
        const int total = NROI * NCH * OUTS * OUTS;
        roi_align_kernel<<<(total + 255) / 256, 256, 0, stream>>>(
            f0, f1, f2, f3, meta, out, total);
    }
}